// Round 1
// baseline (502.246 us; speedup 1.0000x reference)
//
#include <hip/hip_runtime.h>
#include <math.h>

// Problem constants (B=128, S=256, D=128, H=4, Dh=32, L=2, N=255 perfect tree)
namespace {
constexpr int kB = 128, kS = 256, kD = 128, kH = 4;
constexpr float kEps = 1e-6f;
constexpr float kScale = 0.17677669529663687f;  // 1/sqrt(32)
constexpr float kNeg = -1000000000.0f;
}

// ---------------------------------------------------------------------------
// GEMM: out = A(Mx128) @ W(128x128) + bias; optional fused residual + LayerNorm
// block = 256 threads, tile 128(M) x 128(N), BK=32.
// Thread (tx,ty): rows r_i = ty + 16*i, cols c_j = tx + 16*j  (i,j in 0..7).
// Row mapping ty+16*i keeps LDS A-reads in 4 distinct banks (stride-36 pad).
// ---------------------------------------------------------------------------
template <bool FUSE_LN>
__global__ __launch_bounds__(256) void gemm128(
    const float* __restrict__ A, const float* __restrict__ W,
    const float* __restrict__ bias, float* __restrict__ out,
    const float* __restrict__ resid, const float* __restrict__ gamma,
    const float* __restrict__ beta)
{
    __shared__ float As[128][36];   // 36-float stride: 16B-aligned float4 rows
    __shared__ float Bs[32][132];

    const int tid = threadIdx.x;
    const int tx = tid & 15, ty = tid >> 4;
    const size_t m0 = (size_t)blockIdx.x * 128;

    float acc[8][8];
#pragma unroll
    for (int i = 0; i < 8; ++i)
#pragma unroll
        for (int j = 0; j < 8; ++j) acc[i][j] = 0.f;

    const int ra = tid >> 3, ca = (tid & 7) << 2;   // A stage: 32 rows x 8 f4
    const int rb = tid >> 5, cb = (tid & 31) << 2;  // B stage: 8 rows x 32 f4

    for (int k0 = 0; k0 < 128; k0 += 32) {
#pragma unroll
        for (int it = 0; it < 4; ++it) {
            float4 va = *(const float4*)(A + (m0 + ra + 32 * it) * 128 + k0 + ca);
            *(float4*)(&As[ra + 32 * it][ca]) = va;
        }
#pragma unroll
        for (int it = 0; it < 4; ++it) {
            float4 vb = *(const float4*)(W + (size_t)(k0 + rb + 8 * it) * 128 + cb);
            *(float4*)(&Bs[rb + 8 * it][cb]) = vb;
        }
        __syncthreads();
#pragma unroll
        for (int kk = 0; kk < 32; ++kk) {
            float a[8], bb[8];
#pragma unroll
            for (int i = 0; i < 8; ++i) a[i] = As[ty + 16 * i][kk];
#pragma unroll
            for (int j = 0; j < 8; ++j) bb[j] = Bs[kk][tx + 16 * j];
#pragma unroll
            for (int i = 0; i < 8; ++i)
#pragma unroll
                for (int j = 0; j < 8; ++j)
                    acc[i][j] = fmaf(a[i], bb[j], acc[i][j]);
        }
        __syncthreads();
    }

    if (!FUSE_LN) {
#pragma unroll
        for (int i = 0; i < 8; ++i) {
            const size_t r = m0 + ty + 16 * i;
#pragma unroll
            for (int j = 0; j < 8; ++j) {
                const int c = tx + 16 * j;
                out[r * 128 + c] = acc[i][j] + bias[c];
            }
        }
    } else {
        // val = acc + bias + resid; LayerNorm over each 128-col row.
        // Row r is held by the 16 lanes sharing ty -> shfl_xor over tx bits.
#pragma unroll
        for (int i = 0; i < 8; ++i) {
            const size_t r = m0 + ty + 16 * i;
            float vv[8];
            float s = 0.f, s2 = 0.f;
#pragma unroll
            for (int j = 0; j < 8; ++j) {
                const int c = tx + 16 * j;
                float t = acc[i][j] + bias[c] + resid[r * 128 + c];
                vv[j] = t;
                s += t;
                s2 += t * t;
            }
#pragma unroll
            for (int o = 1; o < 16; o <<= 1) {
                s += __shfl_xor(s, o, 64);
                s2 += __shfl_xor(s2, o, 64);
            }
            const float mu = s * (1.f / 128.f);
            const float var = s2 * (1.f / 128.f) - mu * mu;
            const float rs = rsqrtf(var + kEps);
#pragma unroll
            for (int j = 0; j < 8; ++j) {
                const int c = tx + 16 * j;
                out[r * 128 + c] = gamma[c] * (vv[j] - mu) * rs + beta[c];
            }
        }
    }
}

// ---------------------------------------------------------------------------
// Attention: one block per (b,h). K,V staged in LDS (64 KiB), one query row
// per thread, online softmax in registers. ctx may alias q (each block only
// touches its own (b,h) slice; q row is register-resident before any write).
// ---------------------------------------------------------------------------
__global__ __launch_bounds__(256) void attn256(
    const float* __restrict__ q, const float* __restrict__ k,
    const float* __restrict__ v, const float* __restrict__ mask,
    float* __restrict__ ctx)
{
    __shared__ float ks[256][32];
    __shared__ float vs[256][32];

    const int bh = blockIdx.x;
    const int b = bh >> 2, h = bh & 3;
    const int t = threadIdx.x;
    const size_t base = ((size_t)b * 256) * 128 + h * 32;

    // coalesced staging: 8 lanes cover one 128B row chunk
#pragma unroll
    for (int it = 0; it < 8; ++it) {
        const int idx = t + it * 256;
        const int row = idx >> 3;
        const int cg = (idx & 7) << 2;
        *(float4*)(&ks[row][cg]) = *(const float4*)(k + base + (size_t)row * 128 + cg);
        *(float4*)(&vs[row][cg]) = *(const float4*)(v + base + (size_t)row * 128 + cg);
    }
    float4 qr[8];
#pragma unroll
    for (int d = 0; d < 8; ++d)
        qr[d] = *(const float4*)(q + base + (size_t)t * 128 + d * 4);
    __syncthreads();

    const float* mrow = mask + (size_t)b * 256;

    float m = -1e30f, l = 0.f;
    float4 ca[8];
#pragma unroll
    for (int d = 0; d < 8; ++d) ca[d] = make_float4(0.f, 0.f, 0.f, 0.f);

    for (int j = 0; j < 256; ++j) {
        float s = 0.f;
#pragma unroll
        for (int d = 0; d < 8; ++d) {
            const float4 kk = *(const float4*)(&ks[j][d * 4]);  // broadcast read
            s += qr[d].x * kk.x + qr[d].y * kk.y + qr[d].z * kk.z + qr[d].w * kk.w;
        }
        s = s * kScale + mrow[j] * kNeg;
        if (s > m) {  // lazy rescale (rare after warmup)
            const float c = __expf(m - s);
            l *= c;
#pragma unroll
            for (int d = 0; d < 8; ++d) {
                ca[d].x *= c; ca[d].y *= c; ca[d].z *= c; ca[d].w *= c;
            }
            m = s;
        }
        const float p = __expf(s - m);
        l += p;
#pragma unroll
        for (int d = 0; d < 8; ++d) {
            const float4 vv = *(const float4*)(&vs[j][d * 4]);
            ca[d].x = fmaf(p, vv.x, ca[d].x);
            ca[d].y = fmaf(p, vv.y, ca[d].y);
            ca[d].z = fmaf(p, vv.z, ca[d].z);
            ca[d].w = fmaf(p, vv.w, ca[d].w);
        }
    }
    const float inv = 1.f / l;
#pragma unroll
    for (int d = 0; d < 8; ++d) {
        float4 o;
        o.x = ca[d].x * inv; o.y = ca[d].y * inv;
        o.z = ca[d].z * inv; o.w = ca[d].w * inv;
        *(float4*)(ctx + base + (size_t)t * 128 + d * 4) = o;
    }
}

// ---------------------------------------------------------------------------
// Last-row attention weights (final layer) + total_l1 (= L*B*H = 1024 exactly:
// softmax rows are positive and sum to 1, so sum|attn[:,:,-1,:]| = B*H/layer).
// ---------------------------------------------------------------------------
__global__ __launch_bounds__(256) void lastrow_weights(
    const float* __restrict__ q, const float* __restrict__ k,
    const float* __restrict__ mask, float* __restrict__ wout,
    float* __restrict__ l1out)
{
    __shared__ float red[8];
    const int bh = blockIdx.x;
    const int b = bh >> 2, h = bh & 3;
    const int j = threadIdx.x;
    const size_t base = ((size_t)b * 256) * 128 + h * 32;
    const float* qr = q + base + (size_t)255 * 128;
    const float* kr = k + base + (size_t)j * 128;

    float s = 0.f;
#pragma unroll
    for (int d = 0; d < 32; d += 4) {
        const float4 a = *(const float4*)(qr + d);
        const float4 c = *(const float4*)(kr + d);
        s += a.x * c.x + a.y * c.y + a.z * c.z + a.w * c.w;
    }
    s = s * kScale + mask[(size_t)b * 256 + j] * kNeg;

    float mx = s;
#pragma unroll
    for (int o = 1; o < 64; o <<= 1) mx = fmaxf(mx, __shfl_xor(mx, o, 64));
    if ((j & 63) == 0) red[j >> 6] = mx;
    __syncthreads();
    mx = fmaxf(fmaxf(red[0], red[1]), fmaxf(red[2], red[3]));

    const float p = __expf(s - mx);
    float sum = p;
#pragma unroll
    for (int o = 1; o < 64; o <<= 1) sum += __shfl_xor(sum, o, 64);
    if ((j & 63) == 0) red[4 + (j >> 6)] = sum;
    __syncthreads();
    sum = red[4] + red[5] + red[6] + red[7];

    wout[(size_t)bh * 256 + j] = p / sum;
    if (bh == 0 && j == 0) l1out[0] = 1024.0f;
}

// ---------------------------------------------------------------------------
// Tree aggregation (perfect binary tree, 255 nodes, leaves 127..254) fused
// with the y = out1 + tab residual. Block = (b, 32-feature chunk).
// ---------------------------------------------------------------------------
__global__ __launch_bounds__(256) void tree_agg(
    const float* __restrict__ out1, float* __restrict__ y)
{
    __shared__ float e[255 * 32];
    const int b = blockIdx.x;
    const int f0 = blockIdx.y * 32;
    const int tid = threadIdx.x;
    const float* xb = out1 + (size_t)b * 256 * 128 + f0;

    for (int idx = tid; idx < 255 * 32; idx += 256) {
        const int n = idx >> 5, f = idx & 31;
        e[idx] = xb[(size_t)n * 128 + f];
    }
    __syncthreads();

    for (int lvl = 6; lvl >= 0; --lvl) {
        const int p0 = (1 << lvl) - 1;
        const int total = (1 << lvl) * 32;
        for (int w = tid; w < total; w += 256) {
            const int p = p0 + (w >> 5), f = w & 31;
            const float a = e[(2 * p + 1) * 32 + f] + e[(2 * p + 2) * 32 + f];
            e[p * 32 + f] = tanhf(a);
        }
        __syncthreads();
    }

    float* yb = y + (size_t)b * 256 * 128 + f0;
    for (int idx = tid; idx < 256 * 32; idx += 256) {
        const int n = idx >> 5, f = idx & 31;
        const float o = xb[(size_t)n * 128 + f];
        const float tab = (n < 255) ? e[n * 32 + f] : o;  // last pos passes thru
        yb[(size_t)n * 128 + f] = o + tab;
    }
}

// ---------------------------------------------------------------------------
// LayerNorm over 128-float rows: one wave per row, float2 per lane.
// ---------------------------------------------------------------------------
__global__ __launch_bounds__(256) void ln128(
    const float* __restrict__ y, const float* __restrict__ gamma,
    const float* __restrict__ beta, float* __restrict__ xo)
{
    const int row = blockIdx.x * 4 + (threadIdx.x >> 6);
    const int lane = threadIdx.x & 63;
    const float2 vv = *(const float2*)(y + (size_t)row * 128 + lane * 2);
    float s = vv.x + vv.y, s2 = vv.x * vv.x + vv.y * vv.y;
#pragma unroll
    for (int o = 1; o < 64; o <<= 1) {
        s += __shfl_xor(s, o, 64);
        s2 += __shfl_xor(s2, o, 64);
    }
    const float mu = s * (1.f / 128.f);
    const float var = s2 * (1.f / 128.f) - mu * mu;
    const float rs = rsqrtf(var + kEps);
    const float2 g = *(const float2*)(gamma + lane * 2);
    const float2 bb = *(const float2*)(beta + lane * 2);
    float2 o2;
    o2.x = g.x * (vv.x - mu) * rs + bb.x;
    o2.y = g.y * (vv.y - mu) * rs + bb.y;
    *(float2*)(xo + (size_t)row * 128 + lane * 2) = o2;
}

// ---------------------------------------------------------------------------
extern "C" void kernel_launch(void* const* d_in, const int* in_sizes, int n_in,
                              void* d_out, int out_size, void* d_ws, size_t ws_size,
                              hipStream_t stream)
{
    (void)in_sizes; (void)n_in; (void)out_size; (void)ws_size;

    const float* x_in = (const float*)d_in[0];
    const float* mask = (const float*)d_in[1];
    // d_in[2..4] = parent/depth/is_leaf: fixed perfect-tree topology, hardcoded.
    const float* Wq = (const float*)d_in[5];
    const float* bq = (const float*)d_in[6];
    const float* Wk = (const float*)d_in[7];
    const float* bk = (const float*)d_in[8];
    const float* Wv = (const float*)d_in[9];
    const float* bv = (const float*)d_in[10];
    const float* Wo = (const float*)d_in[11];
    const float* bo = (const float*)d_in[12];
    const float* g1 = (const float*)d_in[13];
    const float* b1 = (const float*)d_in[14];
    const float* g2 = (const float*)d_in[15];
    const float* b2 = (const float*)d_in[16];

    const size_t SZ = (size_t)kB * kS * kD;  // 4,194,304 floats
    float* out_x = (float*)d_out;
    float* out_l1 = out_x + SZ;
    float* out_w = out_l1 + 1;

    float* Q  = (float*)d_ws;       // 16 MB each; total ws use = 64 MB
    float* K  = Q + SZ;
    float* V  = K + SZ;
    float* O1 = V + SZ;
    float* CTX = Q;   // attention writes ctx over its own q slice (safe)
    float* Y   = V;   // v is dead once attention completes

    const int mblocks = kB * kS / 128;  // 256

    for (int l = 0; l < 2; ++l) {
        const float* xi = (l == 0) ? x_in : out_x;  // layer-0 x staged in d_out
        const size_t wof = (size_t)l * kD * kD;
        const size_t bof = (size_t)l * kD;

        gemm128<false><<<mblocks, 256, 0, stream>>>(xi, Wq + wof, bq + bof, Q,
                                                    nullptr, nullptr, nullptr);
        gemm128<false><<<mblocks, 256, 0, stream>>>(xi, Wk + wof, bk + bof, K,
                                                    nullptr, nullptr, nullptr);
        gemm128<false><<<mblocks, 256, 0, stream>>>(xi, Wv + wof, bv + bof, V,
                                                    nullptr, nullptr, nullptr);
        if (l == 1)  // before attention clobbers Q with ctx
            lastrow_weights<<<kB * kH, 256, 0, stream>>>(Q, K, mask, out_w, out_l1);
        attn256<<<kB * kH, 256, 0, stream>>>(Q, K, V, mask, CTX);
        gemm128<true><<<mblocks, 256, 0, stream>>>(CTX, Wo + wof, bo + bof, O1,
                                                   xi, g1 + bof, b1 + bof);
        tree_agg<<<dim3(kB, 4), 256, 0, stream>>>(O1, Y);
        ln128<<<kB * kS / 4, 256, 0, stream>>>(Y, g2 + bof, b2 + bof, out_x);
    }
}

// Round 2
// 216.587 us; speedup vs baseline: 2.3189x; 2.3189x over previous
//
#include <hip/hip_runtime.h>
#include <math.h>

typedef __bf16 bf16x8 __attribute__((ext_vector_type(8)));
typedef __bf16 bf16x2 __attribute__((ext_vector_type(2)));
typedef float f32x4 __attribute__((ext_vector_type(4)));

namespace {
constexpr int kB = 128, kS = 256, kD = 128, kH = 4;
constexpr float kEps = 1e-6f;
constexpr float kScale = 0.17677669529663687f;  // 1/sqrt(32)
constexpr float kNeg = -1000000000.0f;
constexpr size_t kSZ = (size_t)kB * kS * kD;    // 4,194,304
}

// ---------------------------------------------------------------------------
// f32 -> bf16 vector convert (8 elems/thread)
// ---------------------------------------------------------------------------
__global__ __launch_bounds__(256) void cvt_bf16(const float* __restrict__ in,
                                                __bf16* __restrict__ out, int n8)
{
    const int i = blockIdx.x * 256 + threadIdx.x;
    if (i < n8) {
        const float4 a = ((const float4*)in)[2 * i];
        const float4 b = ((const float4*)in)[2 * i + 1];
        bf16x8 o;
        o[0] = (__bf16)a.x; o[1] = (__bf16)a.y; o[2] = (__bf16)a.z; o[3] = (__bf16)a.w;
        o[4] = (__bf16)b.x; o[5] = (__bf16)b.y; o[6] = (__bf16)b.z; o[7] = (__bf16)b.w;
        ((bf16x8*)out)[i] = o;
    }
}

// ---------------------------------------------------------------------------
// Weight transpose + convert: Wt[l*4+mtx][n][k] = (bf16) W[l][k][n]
// ---------------------------------------------------------------------------
__global__ __launch_bounds__(256) void wtrans(
    const float* __restrict__ Wq, const float* __restrict__ Wk,
    const float* __restrict__ Wv, const float* __restrict__ Wo,
    __bf16* __restrict__ Wt)
{
    const int mtx = blockIdx.x & 3, l = blockIdx.x >> 2;
    const float* W = (mtx == 0 ? Wq : mtx == 1 ? Wk : mtx == 2 ? Wv : Wo) +
                     (size_t)l * kD * kD;
    __bf16* o = Wt + (size_t)blockIdx.x * kD * kD;
    for (int idx = threadIdx.x; idx < kD * kD; idx += 256) {
        const int k = idx >> 7, n = idx & 127;
        o[n * 128 + k] = (__bf16)W[idx];
    }
}

// ---------------------------------------------------------------------------
// bf16 MFMA GEMM: out(bf16) = A(Mx128 bf16) @ Wt^T + bias.
// MODE 0: plain bf16 out.  MODE 1: + full f32 copy (outf).
// MODE 2: + f32 rows where (m&255)==255 -> outf[m>>8][n] (Q row 255 per b).
// MODE 3: fused (acc+bias+resid) -> LayerNorm -> outf (f32), no bf16 out.
// 256 thr / 4 waves; wave w owns rows [w*32, w*32+32), all 128 cols.
// LDS tiles 128x128 bf16, 16B-chunk XOR swizzle (chunk ^= row&7) for
// conflict-free ds_read_b128 fragment loads (T2).
// Fragment layout (16x16x32): A/B lane = row + 16*(k/8), 8 contiguous k;
// C/D: col = lane&15, row = (lane>>4)*4 + reg (verified m89).
// ---------------------------------------------------------------------------
template <int MODE>
__global__ __launch_bounds__(256) void gemm_mfma(
    const __bf16* __restrict__ A, const __bf16* __restrict__ Wt,
    const float* __restrict__ bias, __bf16* __restrict__ out,
    float* __restrict__ outf, const float* __restrict__ resid,
    const float* __restrict__ gamma, const float* __restrict__ beta)
{
    __shared__ __bf16 As[128 * 128];
    __shared__ __bf16 Ws[128 * 128];

    const int t = threadIdx.x;
    const int w = t >> 6, l = t & 63, lo = l & 15, g = l >> 4;
    const size_t m0 = (size_t)blockIdx.x * 128;

    {   // reg-staged swizzled staging (coalesced 16B global reads)
        const int r0 = t >> 4, c = t & 15;
#pragma unroll
        for (int p = 0; p < 8; ++p) {
            const int row = p * 16 + r0;
            const int cs = c ^ (row & 7);
            *(bf16x8*)&As[row * 128 + cs * 8] =
                *(const bf16x8*)(A + (m0 + row) * 128 + c * 8);
            *(bf16x8*)&Ws[row * 128 + cs * 8] =
                *(const bf16x8*)(Wt + row * 128 + c * 8);
        }
    }
    __syncthreads();

    f32x4 acc[2][8];
#pragma unroll
    for (int mi = 0; mi < 2; ++mi)
#pragma unroll
        for (int ni = 0; ni < 8; ++ni) acc[mi][ni] = f32x4{0.f, 0.f, 0.f, 0.f};

#pragma unroll
    for (int ks = 0; ks < 4; ++ks) {
        bf16x8 av[2], bv[8];
#pragma unroll
        for (int mi = 0; mi < 2; ++mi) {
            const int row = w * 32 + mi * 16 + lo;
            av[mi] = *(const bf16x8*)&As[row * 128 + ((g + 4 * ks) ^ (row & 7)) * 8];
        }
#pragma unroll
        for (int ni = 0; ni < 8; ++ni) {
            const int row = ni * 16 + lo;
            bv[ni] = *(const bf16x8*)&Ws[row * 128 + ((g + 4 * ks) ^ (row & 7)) * 8];
        }
#pragma unroll
        for (int mi = 0; mi < 2; ++mi)
#pragma unroll
            for (int ni = 0; ni < 8; ++ni)
                acc[mi][ni] = __builtin_amdgcn_mfma_f32_16x16x32_bf16(
                    av[mi], bv[ni], acc[mi][ni], 0, 0, 0);
    }

    float bcol[8];
#pragma unroll
    for (int ni = 0; ni < 8; ++ni) bcol[ni] = bias[ni * 16 + lo];

    if constexpr (MODE != 3) {
#pragma unroll
        for (int mi = 0; mi < 2; ++mi)
#pragma unroll
            for (int ni = 0; ni < 8; ++ni)
#pragma unroll
                for (int r = 0; r < 4; ++r) {
                    const size_t m = m0 + w * 32 + mi * 16 + g * 4 + r;
                    const int n = ni * 16 + lo;
                    const float v = acc[mi][ni][r] + bcol[ni];
                    out[m * 128 + n] = (__bf16)v;
                    if constexpr (MODE == 1) outf[m * 128 + n] = v;
                    if constexpr (MODE == 2)
                        if ((m & 255) == 255) outf[(m >> 8) * 128 + n] = v;
                }
    } else {
        float ga[8], be[8];
#pragma unroll
        for (int ni = 0; ni < 8; ++ni) {
            ga[ni] = gamma[ni * 16 + lo];
            be[ni] = beta[ni * 16 + lo];
        }
#pragma unroll
        for (int mi = 0; mi < 2; ++mi) {
            float vv[4][8];
            float s[4] = {0, 0, 0, 0}, s2[4] = {0, 0, 0, 0};
#pragma unroll
            for (int r = 0; r < 4; ++r) {
                const size_t m = m0 + w * 32 + mi * 16 + g * 4 + r;
#pragma unroll
                for (int ni = 0; ni < 8; ++ni) {
                    const float x = acc[mi][ni][r] + bcol[ni] +
                                    resid[m * 128 + ni * 16 + lo];
                    vv[r][ni] = x; s[r] += x; s2[r] += x * x;
                }
            }
#pragma unroll
            for (int r = 0; r < 4; ++r)
#pragma unroll
                for (int o = 1; o < 16; o <<= 1) {
                    s[r] += __shfl_xor(s[r], o, 64);
                    s2[r] += __shfl_xor(s2[r], o, 64);
                }
#pragma unroll
            for (int r = 0; r < 4; ++r) {
                const float mu = s[r] * (1.f / 128.f);
                const float var = s2[r] * (1.f / 128.f) - mu * mu;
                const float rs = rsqrtf(var + kEps);
                const size_t m = m0 + w * 32 + mi * 16 + g * 4 + r;
#pragma unroll
                for (int ni = 0; ni < 8; ++ni) {
                    const int n = ni * 16 + lo;
                    outf[m * 128 + n] = ga[ni] * (vv[r][ni] - mu) * rs + be[ni];
                }
            }
        }
    }
}

// ---------------------------------------------------------------------------
// MFMA attention. Grid 2048 = (b, h, strip). Wave owns 16 queries
// q0 = strip*64 + w*16. S^T = K @ Q^T (16 key-frags, K read from global/L1),
// full softmax in regs (in-lane over 64 + shfl_xor 16/32), P -> LDS bf16
// [16][272] per wave, O = P @ V with V^T LDS tile. No online rescale needed.
// ---------------------------------------------------------------------------
__global__ __launch_bounds__(256) void attn_mfma(
    const __bf16* __restrict__ Qb, const __bf16* __restrict__ Kb,
    const __bf16* __restrict__ Vb, const float* __restrict__ mask,
    __bf16* __restrict__ ctx)
{
    __shared__ __bf16 Pl[4][16][272];   // 256 keys + 16 pad (16B-aligned rows)
    __shared__ __bf16 Vt[32][264];      // V^T: [d][key], pad 8
    __shared__ float mb[256];

    const int t = threadIdx.x;
    const int w = t >> 6, l = t & 63, lo = l & 15, g = l >> 4;
    const int b = blockIdx.x >> 4;
    const int h = (blockIdx.x >> 2) & 3;
    const int strip = blockIdx.x & 3;
    const size_t base = ((size_t)b * 256) * 128 + h * 32;

    mb[t] = mask[b * 256 + t] * kNeg;

    // V^T staging: 16B coalesced reads, scalar transposed LDS writes (once)
#pragma unroll
    for (int p = 0; p < 4; ++p) {
        const int key = p * 64 + (t >> 2);
        const int d0 = (t & 3) * 8;
        const bf16x8 v = *(const bf16x8*)(Vb + base + (size_t)key * 128 + d0);
#pragma unroll
        for (int i = 0; i < 8; ++i) Vt[d0 + i][key] = v[i];
    }

    const int q0 = strip * 64 + w * 16;
    const bf16x8 qf = *(const bf16x8*)(Qb + base + (size_t)(q0 + lo) * 128 + g * 8);
    __syncthreads();

    // S^T[key][q]: A = K (lane: key=lo, k=g*8..), B = Q^T (lane: q=lo, d=g*8..)
    f32x4 s[16];
#pragma unroll
    for (int f = 0; f < 16; ++f) {
        const bf16x8 kf =
            *(const bf16x8*)(Kb + base + (size_t)(f * 16 + lo) * 128 + g * 8);
        s[f] = __builtin_amdgcn_mfma_f32_16x16x32_bf16(
            kf, qf, f32x4{0.f, 0.f, 0.f, 0.f}, 0, 0, 0);
    }

    // scale + mask bias; column max (key = 16f + 4g + r, q = lo)
    float mx = -1e30f;
#pragma unroll
    for (int f = 0; f < 16; ++f) {
        const f32x4 mk = *(const f32x4*)&mb[f * 16 + g * 4];
#pragma unroll
        for (int r = 0; r < 4; ++r) {
            s[f][r] = s[f][r] * kScale + mk[r];
            mx = fmaxf(mx, s[f][r]);
        }
    }
    mx = fmaxf(mx, __shfl_xor(mx, 16, 64));
    mx = fmaxf(mx, __shfl_xor(mx, 32, 64));

    float ls = 0.f;
#pragma unroll
    for (int f = 0; f < 16; ++f)
#pragma unroll
        for (int r = 0; r < 4; ++r) {
            const float p = __expf(s[f][r] - mx);
            s[f][r] = p;
            ls += p;
        }
    ls += __shfl_xor(ls, 16, 64);
    ls += __shfl_xor(ls, 32, 64);

    // P (bf16) -> LDS rows q=lo; keys 16f+4g+{0..3}, packed in pairs
#pragma unroll
    for (int f = 0; f < 16; ++f)
#pragma unroll
        for (int pr = 0; pr < 2; ++pr) {
            bf16x2 pk;
            pk[0] = (__bf16)s[f][2 * pr];
            pk[1] = (__bf16)s[f][2 * pr + 1];
            *(bf16x2*)&Pl[w][lo][f * 16 + g * 4 + 2 * pr] = pk;
        }
    __syncthreads();

    // O = P @ V: A = P (lane: q=lo, key=g*8..), B = V^T rows (lane: d=lo)
    f32x4 o[2] = {f32x4{0.f, 0.f, 0.f, 0.f}, f32x4{0.f, 0.f, 0.f, 0.f}};
#pragma unroll
    for (int ks = 0; ks < 8; ++ks) {
        const bf16x8 pa = *(const bf16x8*)&Pl[w][lo][ks * 32 + g * 8];
#pragma unroll
        for (int nf = 0; nf < 2; ++nf) {
            const bf16x8 bv = *(const bf16x8*)&Vt[nf * 16 + lo][ks * 32 + g * 8];
            o[nf] = __builtin_amdgcn_mfma_f32_16x16x32_bf16(pa, bv, o[nf], 0, 0, 0);
        }
    }

    // normalize + store: C row = q-within-16 = 4g+r, col = d = 16nf+lo
#pragma unroll
    for (int r = 0; r < 4; ++r) {
        const float inv = 1.f / __shfl(ls, 4 * g + r, 64);
        const size_t q = q0 + g * 4 + r;
#pragma unroll
        for (int nf = 0; nf < 2; ++nf)
            ctx[base + q * 128 + nf * 16 + lo] = (__bf16)(o[nf][r] * inv);
    }
}

// ---------------------------------------------------------------------------
// Last-row attention weights (layer 1) from exact f32 Q-row-255 / K buffers.
// total_l1 = L*B*H = 1024 exactly (softmax rows are positive, sum to 1).
// ---------------------------------------------------------------------------
__global__ __launch_bounds__(256) void lastrow_weights(
    const float* __restrict__ Qf, const float* __restrict__ Kf,
    const float* __restrict__ mask, float* __restrict__ wout,
    float* __restrict__ l1out)
{
    __shared__ float red[8];
    const int bh = blockIdx.x;
    const int b = bh >> 2, h = bh & 3;
    const int j = threadIdx.x;
    const float* qr = Qf + (size_t)b * 128 + h * 32;
    const float* kr = Kf + ((size_t)b * 256 + j) * 128 + h * 32;

    float s = 0.f;
#pragma unroll
    for (int d = 0; d < 32; d += 4) {
        const float4 a = *(const float4*)(qr + d);
        const float4 c = *(const float4*)(kr + d);
        s += a.x * c.x + a.y * c.y + a.z * c.z + a.w * c.w;
    }
    s = s * kScale + mask[(size_t)b * 256 + j] * kNeg;

    float mxv = s;
#pragma unroll
    for (int o = 1; o < 64; o <<= 1) mxv = fmaxf(mxv, __shfl_xor(mxv, o, 64));
    if ((j & 63) == 0) red[j >> 6] = mxv;
    __syncthreads();
    mxv = fmaxf(fmaxf(red[0], red[1]), fmaxf(red[2], red[3]));

    const float p = __expf(s - mxv);
    float sum = p;
#pragma unroll
    for (int o = 1; o < 64; o <<= 1) sum += __shfl_xor(sum, o, 64);
    if ((j & 63) == 0) red[4 + (j >> 6)] = sum;
    __syncthreads();
    sum = red[4] + red[5] + red[6] + red[7];

    wout[(size_t)bh * 256 + j] = p / sum;
    if (bh == 0 && j == 0) l1out[0] = 1024.0f;
}

// ---------------------------------------------------------------------------
// Tree aggregation (perfect binary tree, 255 nodes) + y = out1 + tab residual.
// ---------------------------------------------------------------------------
__global__ __launch_bounds__(256) void tree_agg(
    const float* __restrict__ out1, float* __restrict__ y)
{
    __shared__ float e[255 * 32];
    const int b = blockIdx.x;
    const int f0 = blockIdx.y * 32;
    const int tid = threadIdx.x;
    const float* xb = out1 + (size_t)b * 256 * 128 + f0;

    for (int idx = tid; idx < 255 * 32; idx += 256) {
        const int n = idx >> 5, f = idx & 31;
        e[idx] = xb[(size_t)n * 128 + f];
    }
    __syncthreads();

    for (int lvl = 6; lvl >= 0; --lvl) {
        const int p0 = (1 << lvl) - 1;
        const int total = (1 << lvl) * 32;
        for (int wk = tid; wk < total; wk += 256) {
            const int p = p0 + (wk >> 5), f = wk & 31;
            const float a = e[(2 * p + 1) * 32 + f] + e[(2 * p + 2) * 32 + f];
            e[p * 32 + f] = tanhf(a);
        }
        __syncthreads();
    }

    float* yb = y + (size_t)b * 256 * 128 + f0;
    for (int idx = tid; idx < 256 * 32; idx += 256) {
        const int n = idx >> 5, f = idx & 31;
        const float o = xb[(size_t)n * 128 + f];
        const float tab = (n < 255) ? e[n * 32 + f] : o;
        yb[(size_t)n * 128 + f] = o + tab;
    }
}

// ---------------------------------------------------------------------------
// LayerNorm, dual-write f32 (d_out x) + bf16 (next layer's GEMM input)
// ---------------------------------------------------------------------------
__global__ __launch_bounds__(256) void ln128v(
    const float* __restrict__ y, const float* __restrict__ gamma,
    const float* __restrict__ beta, float* __restrict__ xo,
    __bf16* __restrict__ xb)
{
    const int row = blockIdx.x * 4 + (threadIdx.x >> 6);
    const int lane = threadIdx.x & 63;
    const float2 vv = *(const float2*)(y + (size_t)row * 128 + lane * 2);
    float s = vv.x + vv.y, s2 = vv.x * vv.x + vv.y * vv.y;
#pragma unroll
    for (int o = 1; o < 64; o <<= 1) {
        s += __shfl_xor(s, o, 64);
        s2 += __shfl_xor(s2, o, 64);
    }
    const float mu = s * (1.f / 128.f);
    const float var = s2 * (1.f / 128.f) - mu * mu;
    const float rs = rsqrtf(var + kEps);
    const float2 gv = *(const float2*)(gamma + lane * 2);
    const float2 bb = *(const float2*)(beta + lane * 2);
    float2 o2;
    o2.x = gv.x * (vv.x - mu) * rs + bb.x;
    o2.y = gv.y * (vv.y - mu) * rs + bb.y;
    *(float2*)(xo + (size_t)row * 128 + lane * 2) = o2;
    bf16x2 ob;
    ob[0] = (__bf16)o2.x;
    ob[1] = (__bf16)o2.y;
    *(bf16x2*)(xb + (size_t)row * 128 + lane * 2) = ob;
}

// ---------------------------------------------------------------------------
extern "C" void kernel_launch(void* const* d_in, const int* in_sizes, int n_in,
                              void* d_out, int out_size, void* d_ws, size_t ws_size,
                              hipStream_t stream)
{
    (void)in_sizes; (void)n_in; (void)out_size; (void)ws_size;

    const float* x_in = (const float*)d_in[0];
    const float* mask = (const float*)d_in[1];
    const float* Wq = (const float*)d_in[5];
    const float* bq = (const float*)d_in[6];
    const float* Wk = (const float*)d_in[7];
    const float* bk = (const float*)d_in[8];
    const float* Wv = (const float*)d_in[9];
    const float* bv = (const float*)d_in[10];
    const float* Wo = (const float*)d_in[11];
    const float* bo = (const float*)d_in[12];
    const float* g1 = (const float*)d_in[13];
    const float* b1 = (const float*)d_in[14];
    const float* g2 = (const float*)d_in[15];
    const float* b2 = (const float*)d_in[16];

    float* out_x = (float*)d_out;
    float* out_l1 = out_x + kSZ;
    float* out_w = out_l1 + 1;

    // ws layout (59 MB; baseline round used 67 MB of ws successfully):
    char* wsb = (char*)d_ws;
    __bf16* xb = (__bf16*)wsb;                    // [0, 2SZ)
    __bf16* Qb = (__bf16*)(wsb + kSZ * 2);        // [2SZ, 4SZ)
    __bf16* Kb = (__bf16*)(wsb + 2 * kSZ * 2);    // [4SZ, 6SZ)
    __bf16* Vb = (__bf16*)(wsb + 3 * kSZ * 2);    // [6SZ, 8SZ)
    __bf16* CX = (__bf16*)(wsb + 4 * kSZ * 2);    // [8SZ, 10SZ)
    float* O1 = (float*)(wsb + kSZ * 2);          // aliases Qb+Kb (dead post-attn)
    float* Y  = (float*)(wsb + 3 * kSZ * 2);      // aliases Vb+CX (dead post-Oproj)
    __bf16* Wt = (__bf16*)(wsb + 5 * kSZ * 2);    // 8 * 16384 bf16
    float* Qf = (float*)(wsb + 5 * kSZ * 2 + 8 * kD * kD * 2);  // [128][128]
    float* Kf = (float*)((char*)Qf + kB * kD * 4);              // [32768][128]

    cvt_bf16<<<2048, 256, 0, stream>>>(x_in, xb, (int)(kSZ / 8));
    wtrans<<<8, 256, 0, stream>>>(Wq, Wk, Wv, Wo, Wt);

    for (int l = 0; l < 2; ++l) {
        const float* xi = (l == 0) ? x_in : out_x;
        const __bf16* WtL = Wt + (size_t)l * 4 * kD * kD;
        const size_t bof = (size_t)l * kD;

        if (l == 0) {
            gemm_mfma<0><<<256, 256, 0, stream>>>(xb, WtL + 0 * kD * kD, bq + bof,
                                                  Qb, nullptr, nullptr, nullptr, nullptr);
            gemm_mfma<0><<<256, 256, 0, stream>>>(xb, WtL + 1 * kD * kD, bk + bof,
                                                  Kb, nullptr, nullptr, nullptr, nullptr);
        } else {
            gemm_mfma<2><<<256, 256, 0, stream>>>(xb, WtL + 0 * kD * kD, bq + bof,
                                                  Qb, Qf, nullptr, nullptr, nullptr);
            gemm_mfma<1><<<256, 256, 0, stream>>>(xb, WtL + 1 * kD * kD, bk + bof,
                                                  Kb, Kf, nullptr, nullptr, nullptr);
        }
        gemm_mfma<0><<<256, 256, 0, stream>>>(xb, WtL + 2 * kD * kD, bv + bof,
                                              Vb, nullptr, nullptr, nullptr, nullptr);
        if (l == 1)
            lastrow_weights<<<kB * kH, 256, 0, stream>>>(Qf, Kf, mask, out_w, out_l1);

        attn_mfma<<<2048, 256, 0, stream>>>(Qb, Kb, Vb, mask, CX);

        gemm_mfma<3><<<256, 256, 0, stream>>>(CX, WtL + 3 * kD * kD, bo + bof,
                                              nullptr, O1, xi, g1 + bof, b1 + bof);
        tree_agg<<<dim3(kB, 4), 256, 0, stream>>>(O1, Y);
        ln128v<<<kB * kS / 4, 256, 0, stream>>>(Y, g2 + bof, b2 + bof, out_x, xb);
    }
}

// Round 3
// 167.542 us; speedup vs baseline: 2.9977x; 1.2927x over previous
//
#include <hip/hip_runtime.h>
#include <math.h>

typedef __bf16 bf16x8 __attribute__((ext_vector_type(8)));
typedef __bf16 bf16x2 __attribute__((ext_vector_type(2)));
typedef float f32x4 __attribute__((ext_vector_type(4)));

namespace {
constexpr int kB = 128, kS = 256, kD = 128, kH = 4;
constexpr float kEps = 1e-6f;
constexpr float kScale = 0.17677669529663687f;  // 1/sqrt(32)
constexpr float kNeg = -1000000000.0f;
constexpr size_t kSZ = (size_t)kB * kS * kD;    // 4,194,304
}

// ---------------------------------------------------------------------------
// Weight transpose + convert: Wt[l*4+mtx][n][k] = (bf16) W[l][k][n]
// ---------------------------------------------------------------------------
__global__ __launch_bounds__(256) void wtrans(
    const float* __restrict__ Wq, const float* __restrict__ Wk,
    const float* __restrict__ Wv, const float* __restrict__ Wo,
    __bf16* __restrict__ Wt)
{
    const int mtx = blockIdx.x & 3, l = blockIdx.x >> 2;
    const float* W = (mtx == 0 ? Wq : mtx == 1 ? Wk : mtx == 2 ? Wv : Wo) +
                     (size_t)l * kD * kD;
    __bf16* o = Wt + (size_t)blockIdx.x * kD * kD;
    for (int idx = threadIdx.x; idx < kD * kD; idx += 256) {
        const int k = idx >> 7, n = idx & 127;
        o[n * 128 + k] = (__bf16)W[idx];
    }
}

// ---------------------------------------------------------------------------
// Fused QKV GEMM: A (f32, Mx128) staged once -> Q,K,V (bf16) = A@W{q,k,v}^T+b.
// 512 threads / 8 waves; wave owns 16 rows x 128 cols per matrix.
// LDS: As 32KB + 3x Ws 96KB = 128KB, 16B-chunk XOR swizzle (T2).
// ---------------------------------------------------------------------------
__global__ __launch_bounds__(512) void qkv_gemm(
    const float* __restrict__ A, const __bf16* __restrict__ Wt,
    const float* __restrict__ bq, const float* __restrict__ bk,
    const float* __restrict__ bv, __bf16* __restrict__ Qb,
    __bf16* __restrict__ Kb, __bf16* __restrict__ Vb)
{
    __shared__ __bf16 As[128 * 128];
    __shared__ __bf16 Ws[3][128 * 128];

    const int t = threadIdx.x;
    const int w = t >> 6, l = t & 63, lo = l & 15, g = l >> 4;
    const size_t m0 = (size_t)blockIdx.x * 128;

    // stage A: f32 global (2x float4) -> bf16x8 swizzled LDS chunk
#pragma unroll
    for (int p = 0; p < 4; ++p) {
        const int ci = p * 512 + t;
        const int row = ci >> 4, c = ci & 15;
        const float* src = A + (m0 + row) * 128 + c * 8;
        const float4 a0 = *(const float4*)src;
        const float4 a1 = *(const float4*)(src + 4);
        bf16x8 o;
        o[0] = (__bf16)a0.x; o[1] = (__bf16)a0.y; o[2] = (__bf16)a0.z; o[3] = (__bf16)a0.w;
        o[4] = (__bf16)a1.x; o[5] = (__bf16)a1.y; o[6] = (__bf16)a1.z; o[7] = (__bf16)a1.w;
        *(bf16x8*)&As[row * 128 + (c ^ (row & 7)) * 8] = o;
    }
    // stage 3 weight tiles
#pragma unroll
    for (int p = 0; p < 12; ++p) {
        const int ci = p * 512 + t;
        const int m = ci >> 11, r2 = ci & 2047;
        const int row = r2 >> 4, c = r2 & 15;
        *(bf16x8*)&Ws[m][row * 128 + (c ^ (row & 7)) * 8] =
            *(const bf16x8*)(Wt + m * 16384 + row * 128 + c * 8);
    }
    __syncthreads();

    const float* biases[3] = {bq, bk, bv};
    __bf16* outs[3] = {Qb, Kb, Vb};

#pragma unroll
    for (int m = 0; m < 3; ++m) {
        f32x4 acc[8];
#pragma unroll
        for (int ni = 0; ni < 8; ++ni) acc[ni] = f32x4{0.f, 0.f, 0.f, 0.f};

#pragma unroll
        for (int ks = 0; ks < 4; ++ks) {
            const int arow = w * 16 + lo;
            const bf16x8 av =
                *(const bf16x8*)&As[arow * 128 + ((g + 4 * ks) ^ (arow & 7)) * 8];
#pragma unroll
            for (int ni = 0; ni < 8; ++ni) {
                const int brow = ni * 16 + lo;
                const bf16x8 bv8 =
                    *(const bf16x8*)&Ws[m][brow * 128 + ((g + 4 * ks) ^ (brow & 7)) * 8];
                acc[ni] = __builtin_amdgcn_mfma_f32_16x16x32_bf16(av, bv8, acc[ni], 0, 0, 0);
            }
        }
#pragma unroll
        for (int ni = 0; ni < 8; ++ni) {
            const float bc = biases[m][ni * 16 + lo];
#pragma unroll
            for (int r = 0; r < 4; ++r) {
                const size_t mm = m0 + w * 16 + g * 4 + r;
                outs[m][mm * 128 + ni * 16 + lo] = (__bf16)(acc[ni][r] + bc);
            }
        }
    }
}

// ---------------------------------------------------------------------------
// MFMA attention. Grid 2048 = (b, h, strip); wave owns 16 queries.
// S^T = K @ Q^T, full softmax in regs, P->LDS bf16, O = P @ V (V^T tile).
// WEIGHTS: the (strip 3, wave 3) lanes holding q=255 emit the normalized
// softmax row -> wout[b][h][key]; block 0 thread 0 writes total_l1 = 1024
// (exact: softmax rows are positive and sum to 1 -> sum = L*B*H).
// ---------------------------------------------------------------------------
template <int WEIGHTS>
__global__ __launch_bounds__(256) void attn_mfma(
    const __bf16* __restrict__ Qb, const __bf16* __restrict__ Kb,
    const __bf16* __restrict__ Vb, const float* __restrict__ mask,
    __bf16* __restrict__ ctx, float* __restrict__ wout,
    float* __restrict__ l1out)
{
    __shared__ __bf16 Pl[4][16][272];
    __shared__ __bf16 Vt[32][264];
    __shared__ float mb[256];

    const int t = threadIdx.x;
    const int w = t >> 6, l = t & 63, lo = l & 15, g = l >> 4;
    const int b = blockIdx.x >> 4;
    const int h = (blockIdx.x >> 2) & 3;
    const int strip = blockIdx.x & 3;
    const size_t base = ((size_t)b * 256) * 128 + h * 32;

    mb[t] = mask[b * 256 + t] * kNeg;

#pragma unroll
    for (int p = 0; p < 4; ++p) {
        const int key = p * 64 + (t >> 2);
        const int d0 = (t & 3) * 8;
        const bf16x8 v = *(const bf16x8*)(Vb + base + (size_t)key * 128 + d0);
#pragma unroll
        for (int i = 0; i < 8; ++i) Vt[d0 + i][key] = v[i];
    }

    const int q0 = strip * 64 + w * 16;
    const bf16x8 qf = *(const bf16x8*)(Qb + base + (size_t)(q0 + lo) * 128 + g * 8);
    __syncthreads();

    f32x4 s[16];
#pragma unroll
    for (int f = 0; f < 16; ++f) {
        const bf16x8 kf =
            *(const bf16x8*)(Kb + base + (size_t)(f * 16 + lo) * 128 + g * 8);
        s[f] = __builtin_amdgcn_mfma_f32_16x16x32_bf16(
            kf, qf, f32x4{0.f, 0.f, 0.f, 0.f}, 0, 0, 0);
    }

    float mx = -1e30f;
#pragma unroll
    for (int f = 0; f < 16; ++f) {
        const f32x4 mk = *(const f32x4*)&mb[f * 16 + g * 4];
#pragma unroll
        for (int r = 0; r < 4; ++r) {
            s[f][r] = s[f][r] * kScale + mk[r];
            mx = fmaxf(mx, s[f][r]);
        }
    }
    mx = fmaxf(mx, __shfl_xor(mx, 16, 64));
    mx = fmaxf(mx, __shfl_xor(mx, 32, 64));

    float ls = 0.f;
#pragma unroll
    for (int f = 0; f < 16; ++f)
#pragma unroll
        for (int r = 0; r < 4; ++r) {
            const float p = __expf(s[f][r] - mx);
            s[f][r] = p;
            ls += p;
        }
    ls += __shfl_xor(ls, 16, 64);
    ls += __shfl_xor(ls, 32, 64);

    if constexpr (WEIGHTS) {
        // q = q0 + lo = 255 lives in strip 3, wave 3, lo 15 (all 4 g-lanes)
        if (strip == 3 && w == 3 && lo == 15) {
            const float inv = 1.f / ls;
            float* wrow = wout + ((size_t)b * 4 + h) * 256;
#pragma unroll
            for (int f = 0; f < 16; ++f)
#pragma unroll
                for (int r = 0; r < 4; ++r)
                    wrow[f * 16 + g * 4 + r] = s[f][r] * inv;
        }
        if (blockIdx.x == 0 && t == 0) l1out[0] = 1024.0f;
    }

#pragma unroll
    for (int f = 0; f < 16; ++f)
#pragma unroll
        for (int pr = 0; pr < 2; ++pr) {
            bf16x2 pk;
            pk[0] = (__bf16)s[f][2 * pr];
            pk[1] = (__bf16)s[f][2 * pr + 1];
            *(bf16x2*)&Pl[w][lo][f * 16 + g * 4 + 2 * pr] = pk;
        }
    __syncthreads();

    f32x4 o[2] = {f32x4{0.f, 0.f, 0.f, 0.f}, f32x4{0.f, 0.f, 0.f, 0.f}};
#pragma unroll
    for (int ks = 0; ks < 8; ++ks) {
        const bf16x8 pa = *(const bf16x8*)&Pl[w][lo][ks * 32 + g * 8];
#pragma unroll
        for (int nf = 0; nf < 2; ++nf) {
            const bf16x8 bv = *(const bf16x8*)&Vt[nf * 16 + lo][ks * 32 + g * 8];
            o[nf] = __builtin_amdgcn_mfma_f32_16x16x32_bf16(pa, bv, o[nf], 0, 0, 0);
        }
    }

#pragma unroll
    for (int r = 0; r < 4; ++r) {
        const float inv = 1.f / __shfl(ls, 4 * g + r, 64);
        const size_t q = q0 + g * 4 + r;
#pragma unroll
        for (int nf = 0; nf < 2; ++nf)
            ctx[base + q * 128 + nf * 16 + lo] = (__bf16)(o[nf][r] * inv);
    }
}

// ---------------------------------------------------------------------------
// O-projection + residual + LayerNorm1 -> O1 (bf16).
// A = ctx (bf16), resid = x (f32). 512 threads / 8 waves, wave = 16 rows.
// ---------------------------------------------------------------------------
__global__ __launch_bounds__(512) void oproj_ln(
    const __bf16* __restrict__ A, const __bf16* __restrict__ Wt,
    const float* __restrict__ bias, const float* __restrict__ resid,
    const float* __restrict__ gamma, const float* __restrict__ beta,
    __bf16* __restrict__ out)
{
    __shared__ __bf16 As[128 * 128];
    __shared__ __bf16 Ws[128 * 128];

    const int t = threadIdx.x;
    const int w = t >> 6, l = t & 63, lo = l & 15, g = l >> 4;
    const size_t m0 = (size_t)blockIdx.x * 128;

#pragma unroll
    for (int p = 0; p < 4; ++p) {
        const int ci = p * 512 + t;
        const int row = ci >> 4, c = ci & 15;
        const int cs = (c ^ (row & 7)) * 8;
        *(bf16x8*)&As[row * 128 + cs] =
            *(const bf16x8*)(A + (m0 + row) * 128 + c * 8);
        *(bf16x8*)&Ws[row * 128 + cs] =
            *(const bf16x8*)(Wt + row * 128 + c * 8);
    }
    __syncthreads();

    f32x4 acc[8];
#pragma unroll
    for (int ni = 0; ni < 8; ++ni) acc[ni] = f32x4{0.f, 0.f, 0.f, 0.f};

#pragma unroll
    for (int ks = 0; ks < 4; ++ks) {
        const int arow = w * 16 + lo;
        const bf16x8 av =
            *(const bf16x8*)&As[arow * 128 + ((g + 4 * ks) ^ (arow & 7)) * 8];
#pragma unroll
        for (int ni = 0; ni < 8; ++ni) {
            const int brow = ni * 16 + lo;
            const bf16x8 bv8 =
                *(const bf16x8*)&Ws[brow * 128 + ((g + 4 * ks) ^ (brow & 7)) * 8];
            acc[ni] = __builtin_amdgcn_mfma_f32_16x16x32_bf16(av, bv8, acc[ni], 0, 0, 0);
        }
    }

    float bcol[8], ga[8], be[8];
#pragma unroll
    for (int ni = 0; ni < 8; ++ni) {
        bcol[ni] = bias[ni * 16 + lo];
        ga[ni] = gamma[ni * 16 + lo];
        be[ni] = beta[ni * 16 + lo];
    }

    float vv[4][8];
    float s[4] = {0, 0, 0, 0}, s2[4] = {0, 0, 0, 0};
#pragma unroll
    for (int r = 0; r < 4; ++r) {
        const size_t mm = m0 + w * 16 + g * 4 + r;
#pragma unroll
        for (int ni = 0; ni < 8; ++ni) {
            const float x = acc[ni][r] + bcol[ni] + resid[mm * 128 + ni * 16 + lo];
            vv[r][ni] = x; s[r] += x; s2[r] += x * x;
        }
    }
#pragma unroll
    for (int r = 0; r < 4; ++r)
#pragma unroll
        for (int o = 1; o < 16; o <<= 1) {
            s[r] += __shfl_xor(s[r], o, 64);
            s2[r] += __shfl_xor(s2[r], o, 64);
        }
#pragma unroll
    for (int r = 0; r < 4; ++r) {
        const float mu = s[r] * (1.f / 128.f);
        const float var = s2[r] * (1.f / 128.f) - mu * mu;
        const float rs = rsqrtf(var + kEps);
        const size_t mm = m0 + w * 16 + g * 4 + r;
#pragma unroll
        for (int ni = 0; ni < 8; ++ni)
            out[mm * 128 + ni * 16 + lo] =
                (__bf16)(ga[ni] * (vv[r][ni] - mu) * rs + be[ni]);
    }
}

// ---------------------------------------------------------------------------
// Tree aggregation (perfect binary tree, 255 nodes) + y = out1 + tab (bf16 IO,
// f32 LDS internals). Leaves keep e = out1; node 255 passes through.
// ---------------------------------------------------------------------------
__global__ __launch_bounds__(256) void tree_agg(
    const __bf16* __restrict__ o1, __bf16* __restrict__ y)
{
    __shared__ float e[255 * 32];
    const int b = blockIdx.x;
    const int f0 = blockIdx.y * 32;
    const int t = threadIdx.x;
    const __bf16* xb = o1 + (size_t)b * 256 * 128 + f0;

#pragma unroll
    for (int p = 0; p < 4; ++p) {
        const int vidx = p * 256 + t;
        if (vidx < 1020) {
            const int n = vidx >> 2, f8 = (vidx & 3) * 8;
            const bf16x8 v = *(const bf16x8*)(xb + (size_t)n * 128 + f8);
#pragma unroll
            for (int i = 0; i < 8; ++i) e[n * 32 + f8 + i] = (float)v[i];
        }
    }
    __syncthreads();

    for (int lvl = 6; lvl >= 0; --lvl) {
        const int p0 = (1 << lvl) - 1;
        const int total = (1 << lvl) * 32;
        for (int wk = t; wk < total; wk += 256) {
            const int p = p0 + (wk >> 5), f = wk & 31;
            e[p * 32 + f] = tanhf(e[(2 * p + 1) * 32 + f] + e[(2 * p + 2) * 32 + f]);
        }
        __syncthreads();
    }

    __bf16* yb = y + (size_t)b * 256 * 128 + f0;
#pragma unroll
    for (int p = 0; p < 4; ++p) {
        const int vidx = p * 256 + t;
        const int n = vidx >> 2, f8 = (vidx & 3) * 8;
        const bf16x8 v = *(const bf16x8*)(xb + (size_t)n * 128 + f8);
        bf16x8 o;
#pragma unroll
        for (int i = 0; i < 8; ++i) {
            const float ov = (float)v[i];
            const float tab = (n < 255) ? e[n * 32 + f8 + i] : ov;
            o[i] = (__bf16)(ov + tab);
        }
        *(bf16x8*)(yb + (size_t)n * 128 + f8) = o;
    }
}

// ---------------------------------------------------------------------------
// LayerNorm over 128 cols: one wave per row, bf16 in, f32 out (= next x).
// ---------------------------------------------------------------------------
__global__ __launch_bounds__(256) void ln128(
    const __bf16* __restrict__ y, const float* __restrict__ gamma,
    const float* __restrict__ beta, float* __restrict__ xo)
{
    const int row = blockIdx.x * 4 + (threadIdx.x >> 6);
    const int lane = threadIdx.x & 63;
    const bf16x2 v = *(const bf16x2*)(y + (size_t)row * 128 + lane * 2);
    const float vx = (float)v[0], vy = (float)v[1];
    float s = vx + vy, s2 = vx * vx + vy * vy;
#pragma unroll
    for (int o = 1; o < 64; o <<= 1) {
        s += __shfl_xor(s, o, 64);
        s2 += __shfl_xor(s2, o, 64);
    }
    const float mu = s * (1.f / 128.f);
    const float var = s2 * (1.f / 128.f) - mu * mu;
    const float rs = rsqrtf(var + kEps);
    const float2 gv = *(const float2*)(gamma + lane * 2);
    const float2 bb = *(const float2*)(beta + lane * 2);
    float2 o2;
    o2.x = gv.x * (vx - mu) * rs + bb.x;
    o2.y = gv.y * (vy - mu) * rs + bb.y;
    *(float2*)(xo + (size_t)row * 128 + lane * 2) = o2;
}

// ---------------------------------------------------------------------------
extern "C" void kernel_launch(void* const* d_in, const int* in_sizes, int n_in,
                              void* d_out, int out_size, void* d_ws, size_t ws_size,
                              hipStream_t stream)
{
    (void)in_sizes; (void)n_in; (void)out_size; (void)ws_size;

    const float* x_in = (const float*)d_in[0];
    const float* mask = (const float*)d_in[1];
    const float* Wq = (const float*)d_in[5];
    const float* bq = (const float*)d_in[6];
    const float* Wk = (const float*)d_in[7];
    const float* bk = (const float*)d_in[8];
    const float* Wv = (const float*)d_in[9];
    const float* bv = (const float*)d_in[10];
    const float* Wo = (const float*)d_in[11];
    const float* bo = (const float*)d_in[12];
    const float* g1 = (const float*)d_in[13];
    const float* b1 = (const float*)d_in[14];
    const float* g2 = (const float*)d_in[15];
    const float* b2 = (const float*)d_in[16];

    float* out_x = (float*)d_out;
    float* out_l1 = out_x + kSZ;
    float* out_w = out_l1 + 1;

    // ws: 6 bf16 buffers of 8MB + weight tiles (48.3 MB total)
    char* wsb = (char*)d_ws;
    __bf16* Qb = (__bf16*)wsb;
    __bf16* Kb = (__bf16*)(wsb + 1 * kSZ * 2);
    __bf16* Vb = (__bf16*)(wsb + 2 * kSZ * 2);
    __bf16* CX = (__bf16*)(wsb + 3 * kSZ * 2);
    __bf16* O1 = (__bf16*)(wsb + 4 * kSZ * 2);
    __bf16* Y  = (__bf16*)(wsb + 5 * kSZ * 2);
    __bf16* Wt = (__bf16*)(wsb + 6 * kSZ * 2);   // 8 * 16384 bf16

    wtrans<<<8, 256, 0, stream>>>(Wq, Wk, Wv, Wo, Wt);

    for (int l = 0; l < 2; ++l) {
        const float* xi = (l == 0) ? x_in : out_x;
        const __bf16* WtL = Wt + (size_t)l * 4 * kD * kD;
        const size_t bof = (size_t)l * kD;

        qkv_gemm<<<256, 512, 0, stream>>>(xi, WtL, bq + bof, bk + bof, bv + bof,
                                          Qb, Kb, Vb);
        if (l == 0)
            attn_mfma<0><<<2048, 256, 0, stream>>>(Qb, Kb, Vb, mask, CX,
                                                   nullptr, nullptr);
        else
            attn_mfma<1><<<2048, 256, 0, stream>>>(Qb, Kb, Vb, mask, CX,
                                                   out_w, out_l1);
        oproj_ln<<<256, 512, 0, stream>>>(CX, WtL + 3 * kD * kD, bo + bof, xi,
                                          g1 + bof, b1 + bof, O1);
        tree_agg<<<dim3(kB, 4), 256, 0, stream>>>(O1, Y);
        ln128<<<kB * kS / 4, 256, 0, stream>>>(Y, g2 + bof, b2 + bof, out_x);
    }
}